// Round 4
// baseline (1005.693 us; speedup 1.0000x reference)
//
#include <hip/hip_runtime.h>
#include <math.h>

// Problem constants
#define BB 4
#define DIM 192
#define HEADS 4
#define CH 48            // DIM/HEADS
#define HW 16384         // 128*128
#define C3 576           // 3*DIM

// ---------------- fp32 tiled GEMM: C[M,N] = A[M,K] @ B[K,N] ----------------
// block 256 threads, tile 64x64, K-tile 16, 4x4 micro-tile per thread.
// M % 64 == 0, N % 64 == 0, K % 16 == 0.
__global__ __launch_bounds__(256) void gemm_f32(
    const float* __restrict__ A, const float* __restrict__ B, float* __restrict__ C,
    int M, int N, int K)
{
    __shared__ float As[16][64];   // [k][m]
    __shared__ float Bs[16][64];   // [k][n]
    int t  = threadIdx.x;
    int tx = t & 15, ty = t >> 4;
    int m0 = blockIdx.y * 64, n0 = blockIdx.x * 64;
    float acc[4][4] = {};
    int am = t >> 2, ak = (t & 3) * 4;     // A loader: 64 m x 16 k
    int bk = t >> 4, bn = (t & 15) * 4;    // B loader: 16 k x 64 n
    for (int k0 = 0; k0 < K; k0 += 16) {
        float4 av = *(const float4*)(A + (long)(m0 + am) * K + k0 + ak);
        float4 bv = *(const float4*)(B + (long)(k0 + bk) * N + n0 + bn);
        __syncthreads();
        As[ak + 0][am] = av.x; As[ak + 1][am] = av.y;
        As[ak + 2][am] = av.z; As[ak + 3][am] = av.w;
        *(float4*)&Bs[bk][bn] = bv;
        __syncthreads();
#pragma unroll
        for (int k = 0; k < 16; ++k) {
            float4 a4 = *(const float4*)&As[k][ty * 4];
            float4 b4 = *(const float4*)&Bs[k][tx * 4];
            float a[4] = {a4.x, a4.y, a4.z, a4.w};
            float b[4] = {b4.x, b4.y, b4.z, b4.w};
#pragma unroll
            for (int i = 0; i < 4; ++i)
#pragma unroll
                for (int j = 0; j < 4; ++j) acc[i][j] += a[i] * b[j];
        }
    }
#pragma unroll
    for (int i = 0; i < 4; ++i) {
        float4 v = {acc[i][0], acc[i][1], acc[i][2], acc[i][3]};
        *(float4*)(C + (long)(m0 + ty * 4 + i) * N + n0 + tx * 4) = v;
    }
}

// ---------------- Depthwise 3x3, pad 1 (per-chunk; channel = blockIdx.y local) ----------------
__global__ __launch_bounds__(256) void dwconv3x3(
    const float* __restrict__ in, const float* __restrict__ w, float* __restrict__ out)
{
    int c = blockIdx.y;                       // local channel within chunk
    long base = (long)c * HW;
    int p = blockIdx.x * 256 + threadIdx.x;   // 0..16383
    int y = p >> 7, x = p & 127;
    const float* wc = w + c * 9;
    float s = 0.f;
#pragma unroll
    for (int dy = 0; dy < 3; ++dy) {
        int yy = y + dy - 1;
        if (yy < 0 || yy > 127) continue;
#pragma unroll
        for (int dx = 0; dx < 3; ++dx) {
            int xx = x + dx - 1;
            if (xx < 0 || xx > 127) continue;
            s += in[base + yy * 128 + xx] * wc[dy * 3 + dx];
        }
    }
    out[base + p] = s;
}

// ---------------- Row inverse norms for q (which=0) and k (which=1), one batch ----------------
__global__ __launch_bounds__(256) void rownorm(
    const float* __restrict__ dw, float* __restrict__ norms)
{
    int which = blockIdx.y;            // 0=q, 1=k
    int r = blockIdx.x;                // 0..191
    const float* p = dw + ((long)which * DIM + r) * HW;
    int t = threadIdx.x;
    float s = 0.f;
#pragma unroll
    for (int i = 0; i < 16; ++i) {
        float4 v = *(const float4*)(p + (t + i * 256) * 4);
        s += v.x * v.x + v.y * v.y + v.z * v.z + v.w * v.w;
    }
    __shared__ float red[256];
    red[t] = s; __syncthreads();
    for (int off = 128; off > 0; off >>= 1) {
        if (t < off) red[t] += red[t + off];
        __syncthreads();
    }
    if (t == 0) {
        float n = sqrtf(red[0]);
        norms[which * DIM + r] = 1.0f / fmaxf(n, 1e-12f);
    }
}

__global__ void zero_buf(float* __restrict__ p, int n) {
    int i = blockIdx.x * 256 + threadIdx.x;
    if (i < n) p[i] = 0.f;
}

// ---------------- attn_raw[h,c,d] += partial QK^T over one 128-wide n-chunk ----------------
__global__ __launch_bounds__(256) void attn_partial(
    const float* __restrict__ dw, float* __restrict__ attn_raw)
{
    int h = blockIdx.y;                // head
    int n0 = blockIdx.x * 128;
    __shared__ float qs[48][132];      // +4 pad to break bank conflicts
    __shared__ float ks[48][132];
    const float* qbase = dw + (long)(h * CH) * HW + n0;
    const float* kbase = dw + (long)(DIM + h * CH) * HW + n0;
    int t = threadIdx.x;
#pragma unroll
    for (int i = 0; i < 6; ++i) {
        int f = t + i * 256;           // 1536 float4 slots = 48 rows x 32
        int row = f >> 5;
        int c4 = (f & 31) * 4;
        float4 qv = *(const float4*)(qbase + (long)row * HW + c4);
        float4 kv = *(const float4*)(kbase + (long)row * HW + c4);
        *(float4*)&qs[row][c4] = qv;
        *(float4*)&ks[row][c4] = kv;
    }
    __syncthreads();
    int tx = t & 15, ty = t >> 4;
    int c0 = ty * 3, d0 = tx * 3;
    float acc[3][3] = {};
    for (int nv = 0; nv < 32; ++nv) {
        float4 qa[3], kb[3];
#pragma unroll
        for (int i = 0; i < 3; ++i) qa[i] = *(const float4*)&qs[c0 + i][nv * 4];
#pragma unroll
        for (int j = 0; j < 3; ++j) kb[j] = *(const float4*)&ks[d0 + j][nv * 4];
#pragma unroll
        for (int i = 0; i < 3; ++i)
#pragma unroll
            for (int j = 0; j < 3; ++j)
                acc[i][j] += qa[i].x * kb[j].x + qa[i].y * kb[j].y
                           + qa[i].z * kb[j].z + qa[i].w * kb[j].w;
    }
#pragma unroll
    for (int i = 0; i < 3; ++i)
#pragma unroll
        for (int j = 0; j < 3; ++j)
            atomicAdd(&attn_raw[((long)h * CH + c0 + i) * CH + d0 + j], acc[i][j]);
}

// ---------------- per-row top-k softmax combine (one batch, 192 rows) ----------------
__global__ void topk_combine(
    const float* __restrict__ attn_raw, const float* __restrict__ norms,
    const float* __restrict__ temp, const float* __restrict__ attn_w,
    float* __restrict__ Wc)
{
    int rid = threadIdx.x;             // 0..191 = h*48 + c
    if (rid >= HEADS * CH) return;
    int c = rid % CH;
    int h = rid / CH;
    const float* row = attn_raw + (long)rid * CH;
    float invq = norms[h * CH + c];
    float tmp = temp[h];
    float a[48];
    for (int d = 0; d < 48; ++d)
        a[d] = row[d] * invq * norms[DIM + h * CH + d] * tmp;
    float m = -INFINITY;
    for (int d = 0; d < 48; ++d) m = fmaxf(m, a[d]);
    // k values: int(48 * rate) in IEEE double: 48*(2/3) = 32 - 2^-49 which
    // rounds HALF-TO-EVEN up to exactly 32.0 -> int = 32 (not 31!).
    // {int(24.0), int(32.0), int(36.0), int(38.400000000000006)} = {24,32,36,38}
    const int kv[4] = {24, 32, 36, 38};
    float e[48]; int rank[48];
    float den[4] = {0, 0, 0, 0};
    for (int d = 0; d < 48; ++d) {
        e[d] = expf(a[d] - m);
        int r = 0;
        for (int j = 0; j < 48; ++j)
            r += (a[j] > a[d]) || (a[j] == a[d] && j < d);
        rank[d] = r;
        for (int i = 0; i < 4; ++i)
            if (r < kv[i]) den[i] += e[d];
    }
    float wsum[4];
    for (int i = 0; i < 4; ++i) wsum[i] = attn_w[i] / den[i];
    for (int d = 0; d < 48; ++d) {
        float s = 0.f;
        for (int i = 0; i < 4; ++i)
            if (rank[d] < kv[i]) s += wsum[i];
        Wc[(long)rid * CH + d] = e[d] * s;
    }
}

// ---------------- M[o, h*48+d] = sum_ch wproj[o, h*48+ch] * Wc[h,ch,d]  (one batch) ----------------
__global__ __launch_bounds__(256) void build_m(
    const float* __restrict__ wproj, const float* __restrict__ Wc,
    float* __restrict__ Mmat)
{
    int idx = blockIdx.x * 256 + threadIdx.x;   // 0..192*192-1
    if (idx >= DIM * DIM) return;
    int cg = idx % DIM;
    int o  = idx / DIM;
    int h = cg / CH, d = cg % CH;
    const float* wp = wproj + o * DIM + h * CH;
    const float* wcc = Wc + (long)h * CH * CH + d;
    float s = 0.f;
#pragma unroll
    for (int ch = 0; ch < CH; ++ch) s += wp[ch] * wcc[ch * CH];
    Mmat[idx] = s;
}

extern "C" void kernel_launch(void* const* d_in, const int* in_sizes, int n_in,
                              void* d_out, int out_size, void* d_ws, size_t ws_size,
                              hipStream_t stream) {
    const float* x      = (const float*)d_in[0];   // [4,192,128,128]
    const float* w_qkv  = (const float*)d_in[1];   // [576,192]
    const float* w_dw   = (const float*)d_in[2];   // [576,9]
    const float* w_proj = (const float*)d_in[3];   // [192,192]
    const float* temper = (const float*)d_in[4];   // [4]
    const float* attn_w = (const float*)d_in[5];   // [4]
    float* out = (float*)d_out;                    // [4,192,128,128]

    // Workspace layout (per-batch reuse). dw = 576*16384 floats (37.75 MB).
    float* dw       = (float*)d_ws;
    float* norms    = dw + (long)C3 * HW;       // 384 floats (pad to 512)
    float* attn_raw = norms + 512;              // 9216 floats
    float* Wc       = attn_raw + 9216;          // 9216 floats
    float* Mmat     = Wc + 9216;                // 36864 floats
    float* pre      = Mmat + 36864;             // chunk_M * HW floats
    // Choose chunk for the qkv-GEMM -> dwconv stage based on available space.
    long fixed_floats = (long)(pre - dw);
    long avail = ((long)ws_size / 4) - fixed_floats;
    int chunk = 64;                             // minimum: +4.2 MB
    if (avail >= (long)C3 * HW)      chunk = C3;    // +37.75 MB (one shot)
    else if (avail >= (long)192 * HW) chunk = 192;  // +12.6 MB

    for (int b = 0; b < BB; ++b) {
        const float* xb = x + (long)b * DIM * HW;
        float* outb = out + (long)b * DIM * HW;

        // 1+2. qkv 1x1 conv ([576,192]@[192,16384]) + depthwise 3x3, chunked over channels
        for (int c0 = 0; c0 < C3; c0 += chunk) {
            gemm_f32<<<dim3(HW / 64, chunk / 64), 256, 0, stream>>>(
                w_qkv + (long)c0 * DIM, xb, pre, chunk, HW, DIM);
            dwconv3x3<<<dim3(HW / 256, chunk), 256, 0, stream>>>(
                pre, w_dw + (long)c0 * 9, dw + (long)c0 * HW);
        }
        // 3. inverse L2 norms of q,k rows
        rownorm<<<dim3(DIM, 2), 256, 0, stream>>>(dw, norms);
        // 4. QK^T (split-N, atomic accumulate)
        zero_buf<<<36, 256, 0, stream>>>(attn_raw, HEADS * CH * CH);
        attn_partial<<<dim3(HW / 128, HEADS), 256, 0, stream>>>(dw, attn_raw);
        // 5. top-k softmax combine
        topk_combine<<<1, 192, 0, stream>>>(attn_raw, norms, temper, attn_w, Wc);
        // 6. fold proj into [192,192]
        build_m<<<(DIM * DIM + 255) / 256, 256, 0, stream>>>(w_proj, Wc, Mmat);
        // 7. out[b] = M @ v
        gemm_f32<<<dim3(HW / 64, DIM / 64), 256, 0, stream>>>(
            Mmat, dw + (long)2 * DIM * HW, outb, DIM, HW, DIM);
    }
}

// Round 5
// 579.897 us; speedup vs baseline: 1.7343x; 1.7343x over previous
//
#include <hip/hip_runtime.h>
#include <math.h>
#include <stdint.h>

// Problem constants
#define BB 4
#define DIM 192
#define HEADS 4
#define CH 48            // DIM/HEADS
#define HW 16384         // 128*128
#define C3 576           // 3*DIM

typedef unsigned short ushort_t;
typedef __attribute__((ext_vector_type(8))) short short8;
typedef __attribute__((ext_vector_type(4))) float floatx4;

__device__ __forceinline__ ushort_t f2bf(float f) {  // RNE
    union { float f; unsigned int i; } v; v.f = f;
    unsigned int x = v.i;
    x += 0x7fffu + ((x >> 16) & 1u);
    return (ushort_t)(x >> 16);
}

// ---------------- elementwise fp32 -> bf16 ----------------
__global__ __launch_bounds__(256) void convert_bf16(
    const float* __restrict__ in, ushort_t* __restrict__ out, int n)
{
    int i = blockIdx.x * 256 + threadIdx.x;
    if (i < n) out[i] = f2bf(in[i]);
}

// ---------------- transpose + convert: in fp32 [192][16384] -> out bf16 [16384][192] ----------------
// grid (16384/64, 192/64), block 256
__global__ __launch_bounds__(256) void tconv(
    const float* __restrict__ in, ushort_t* __restrict__ out)
{
    __shared__ ushort_t tile[64][80];   // [n_local][k_local], pad to 80 for aligned b128
    int n0 = blockIdx.x * 64, k0 = blockIdx.y * 64;
    int t = threadIdx.x;
#pragma unroll
    for (int i = 0; i < 4; ++i) {
        int kl = (t >> 4) + 16 * i;
        float4 v = *(const float4*)(in + (long)(k0 + kl) * HW + n0 + (t & 15) * 4);
        int nl = (t & 15) * 4;
        tile[nl + 0][kl] = f2bf(v.x); tile[nl + 1][kl] = f2bf(v.y);
        tile[nl + 2][kl] = f2bf(v.z); tile[nl + 3][kl] = f2bf(v.w);
    }
    __syncthreads();
#pragma unroll
    for (int i = 0; i < 2; ++i) {
        int nl = t >> 2, seg = (t & 3) + 4 * i;
        *(uint4*)(out + (long)(n0 + nl) * DIM + k0 + seg * 8) = *(uint4*)&tile[nl][seg * 8];
    }
}

// ---------------- MFMA GEMM: C[M][N] f32 = A[M][K]bf16 @ B via BT[N][K]bf16 ----------------
// grid (N/128, M/64), block 256 = 4 waves (2 m-halves x 2 n-halves), wave = 32m x 64n
// K % 32 == 0, M % 64 == 0, N % 128 == 0
__global__ __launch_bounds__(256) void gemm_mfma(
    const ushort_t* __restrict__ A, const ushort_t* __restrict__ BT,
    float* __restrict__ C, int M, int N, int K)
{
    __shared__ ushort_t As[64][40];    // [m][k], 80 B row stride (16B-aligned)
    __shared__ ushort_t Bs[128][40];   // [n][k]
    int t = threadIdx.x;
    int wave = t >> 6, lane = t & 63;
    int l15 = lane & 15, quad = lane >> 4;
    int m0 = blockIdx.y * 64, n0 = blockIdx.x * 128;
    int wm = (wave & 1) * 32, wn = (wave >> 1) * 64;
    floatx4 acc[2][4];
#pragma unroll
    for (int i = 0; i < 2; ++i)
#pragma unroll
        for (int j = 0; j < 4; ++j) acc[i][j] = (floatx4){0.f, 0.f, 0.f, 0.f};

    int ar = t >> 2, aseg = (t & 3) * 8;    // stager: row, 8-elem segment
    for (int k0 = 0; k0 < K; k0 += 32) {
        uint4 va  = *(const uint4*)(A  + (long)(m0 + ar) * K + k0 + aseg);
        uint4 vb0 = *(const uint4*)(BT + (long)(n0 + ar) * K + k0 + aseg);
        uint4 vb1 = *(const uint4*)(BT + (long)(n0 + ar + 64) * K + k0 + aseg);
        __syncthreads();
        *(uint4*)&As[ar][aseg] = va;
        *(uint4*)&Bs[ar][aseg] = vb0;
        *(uint4*)&Bs[ar + 64][aseg] = vb1;
        __syncthreads();
        short8 af[2], bf[4];
#pragma unroll
        for (int mi = 0; mi < 2; ++mi)
            af[mi] = *(const short8*)&As[wm + mi * 16 + l15][quad * 8];
#pragma unroll
        for (int ni = 0; ni < 4; ++ni)
            bf[ni] = *(const short8*)&Bs[wn + ni * 16 + l15][quad * 8];
#pragma unroll
        for (int mi = 0; mi < 2; ++mi)
#pragma unroll
            for (int ni = 0; ni < 4; ++ni)
                acc[mi][ni] = __builtin_amdgcn_mfma_f32_16x16x32_bf16(
                    af[mi], bf[ni], acc[mi][ni], 0, 0, 0);
    }
    // C/D layout: col = lane&15, row = quad*4 + reg
#pragma unroll
    for (int mi = 0; mi < 2; ++mi)
#pragma unroll
        for (int ni = 0; ni < 4; ++ni) {
            long base = (long)(m0 + wm + mi * 16 + quad * 4) * N + n0 + wn + ni * 16 + l15;
#pragma unroll
            for (int r = 0; r < 4; ++r)
                C[base + (long)r * N] = acc[mi][ni][r];
        }
}

// ---------------- Depthwise 3x3, pad 1 ----------------
__global__ __launch_bounds__(256) void dwconv3x3(
    const float* __restrict__ in, const float* __restrict__ w, float* __restrict__ out)
{
    int c = blockIdx.y;                       // local channel within chunk
    long base = (long)c * HW;
    int p = blockIdx.x * 256 + threadIdx.x;
    int y = p >> 7, x = p & 127;
    const float* wc = w + c * 9;
    float s = 0.f;
#pragma unroll
    for (int dy = 0; dy < 3; ++dy) {
        int yy = y + dy - 1;
        if (yy < 0 || yy > 127) continue;
#pragma unroll
        for (int dx = 0; dx < 3; ++dx) {
            int xx = x + dx - 1;
            if (xx < 0 || xx > 127) continue;
            s += in[base + yy * 128 + xx] * wc[dy * 3 + dx];
        }
    }
    out[base + p] = s;
}

// ---------------- Row inverse norms for q (which=0) and k (which=1) ----------------
__global__ __launch_bounds__(256) void rownorm(
    const float* __restrict__ dw, float* __restrict__ norms)
{
    int which = blockIdx.y;
    int r = blockIdx.x;
    const float* p = dw + ((long)which * DIM + r) * HW;
    int t = threadIdx.x;
    float s = 0.f;
#pragma unroll
    for (int i = 0; i < 16; ++i) {
        float4 v = *(const float4*)(p + (t + i * 256) * 4);
        s += v.x * v.x + v.y * v.y + v.z * v.z + v.w * v.w;
    }
    __shared__ float red[256];
    red[t] = s; __syncthreads();
    for (int off = 128; off > 0; off >>= 1) {
        if (t < off) red[t] += red[t + off];
        __syncthreads();
    }
    if (t == 0) {
        float n = sqrtf(red[0]);
        norms[which * DIM + r] = 1.0f / fmaxf(n, 1e-12f);
    }
}

__global__ void zero_buf(float* __restrict__ p, int n) {
    int i = blockIdx.x * 256 + threadIdx.x;
    if (i < n) p[i] = 0.f;
}

// ---------------- attn_raw[h,c,d] += partial QK^T over one 128-wide n-chunk ----------------
__global__ __launch_bounds__(256) void attn_partial(
    const float* __restrict__ dw, float* __restrict__ attn_raw)
{
    int h = blockIdx.y;
    int n0 = blockIdx.x * 128;
    __shared__ float qs[48][132];
    __shared__ float ks[48][132];
    const float* qbase = dw + (long)(h * CH) * HW + n0;
    const float* kbase = dw + (long)(DIM + h * CH) * HW + n0;
    int t = threadIdx.x;
#pragma unroll
    for (int i = 0; i < 6; ++i) {
        int f = t + i * 256;
        int row = f >> 5;
        int c4 = (f & 31) * 4;
        float4 qv = *(const float4*)(qbase + (long)row * HW + c4);
        float4 kv = *(const float4*)(kbase + (long)row * HW + c4);
        *(float4*)&qs[row][c4] = qv;
        *(float4*)&ks[row][c4] = kv;
    }
    __syncthreads();
    int tx = t & 15, ty = t >> 4;
    int c0 = ty * 3, d0 = tx * 3;
    float acc[3][3] = {};
    for (int nv = 0; nv < 32; ++nv) {
        float4 qa[3], kb[3];
#pragma unroll
        for (int i = 0; i < 3; ++i) qa[i] = *(const float4*)&qs[c0 + i][nv * 4];
#pragma unroll
        for (int j = 0; j < 3; ++j) kb[j] = *(const float4*)&ks[d0 + j][nv * 4];
#pragma unroll
        for (int i = 0; i < 3; ++i)
#pragma unroll
            for (int j = 0; j < 3; ++j)
                acc[i][j] += qa[i].x * kb[j].x + qa[i].y * kb[j].y
                           + qa[i].z * kb[j].z + qa[i].w * kb[j].w;
    }
#pragma unroll
    for (int i = 0; i < 3; ++i)
#pragma unroll
        for (int j = 0; j < 3; ++j)
            atomicAdd(&attn_raw[((long)h * CH + c0 + i) * CH + d0 + j], acc[i][j]);
}

// ---------------- top-k softmax combine: one WAVE per row, one lane per element ----------------
// grid 48 blocks x 256 threads (4 waves = 4 rows/block); no register arrays -> no spill
__global__ __launch_bounds__(256) void topk_combine2(
    const float* __restrict__ attn_raw, const float* __restrict__ norms,
    const float* __restrict__ temp, const float* __restrict__ attn_w,
    float* __restrict__ Wc)
{
    int wave = threadIdx.x >> 6, lane = threadIdx.x & 63;
    int rid = blockIdx.x * 4 + wave;   // 0..191 = h*48 + c
    int c = rid % CH, h = rid / CH;
    int d = lane;
    float a = -INFINITY;
    if (d < 48)
        a = attn_raw[(long)rid * CH + d] * norms[h * CH + c]
          * norms[DIM + h * CH + d] * temp[h];
    // wave max
    float m = a;
#pragma unroll
    for (int off = 32; off > 0; off >>= 1) m = fmaxf(m, __shfl_xor(m, off, 64));
    float e = (d < 48) ? expf(a - m) : 0.f;
    // rank = #{a_j > a_d} + #{j<d : a_j == a_d}
    int rank = 0;
    for (int j = 0; j < 48; ++j) {
        float aj = __shfl(a, j, 64);
        rank += (aj > a) || (aj == a && j < d);
    }
    // k = int(48*rate) in IEEE double: {24, 32, 36, 38} (48*(2/3) rounds UP to 32.0)
    const int kv[4] = {24, 32, 36, 38};
    float s = 0.f;
#pragma unroll
    for (int i = 0; i < 4; ++i) {
        float contrib = (d < 48 && rank < kv[i]) ? e : 0.f;
#pragma unroll
        for (int off = 32; off > 0; off >>= 1) contrib += __shfl_xor(contrib, off, 64);
        s += (rank < kv[i]) ? attn_w[i] / contrib : 0.f;
    }
    if (d < 48) Wc[(long)rid * CH + d] = e * s;
}

// ---------------- M[o, h*48+d] = sum_ch wproj[o, h*48+ch] * Wc[h,ch,d] -> bf16 ----------------
__global__ __launch_bounds__(256) void build_m(
    const float* __restrict__ wproj, const float* __restrict__ Wc,
    ushort_t* __restrict__ Mb)
{
    int idx = blockIdx.x * 256 + threadIdx.x;
    if (idx >= DIM * DIM) return;
    int cg = idx % DIM;
    int o  = idx / DIM;
    int h = cg / CH, d = cg % CH;
    const float* wp = wproj + o * DIM + h * CH;
    const float* wcc = Wc + (long)h * CH * CH + d;
    float s = 0.f;
#pragma unroll
    for (int ch = 0; ch < CH; ++ch) s += wp[ch] * wcc[ch * CH];
    Mb[idx] = f2bf(s);
}

extern "C" void kernel_launch(void* const* d_in, const int* in_sizes, int n_in,
                              void* d_out, int out_size, void* d_ws, size_t ws_size,
                              hipStream_t stream) {
    const float* x      = (const float*)d_in[0];   // [4,192,128,128]
    const float* w_qkv  = (const float*)d_in[1];   // [576,192]
    const float* w_dw   = (const float*)d_in[2];   // [576,9]
    const float* w_proj = (const float*)d_in[3];   // [192,192]
    const float* temper = (const float*)d_in[4];   // [4]
    const float* attn_w = (const float*)d_in[5];   // [4]
    float* out = (float*)d_out;                    // [4,192,128,128]

    // Workspace layout (per-batch reuse); all offsets 16B-aligned.
    char* p = (char*)d_ws;
    float* dw        = (float*)p;            p += (long)C3 * HW * 4;      // 37.75 MB
    ushort_t* xT     = (ushort_t*)p;         p += (long)HW * DIM * 2;     // 6.29 MB (shared with vT)
    ushort_t* vT     = xT;                                                // reuse: xT dead before vT written
    ushort_t* wqb    = (ushort_t*)p;         p += (long)C3 * DIM * 2;     // 221 KB
    float* norms     = (float*)p;            p += 2048;
    float* attn_raw  = (float*)p;            p += 9216 * 4;
    float* Wc        = (float*)p;            p += 9216 * 4;
    ushort_t* Mb     = (ushort_t*)p;         p += (long)DIM * DIM * 2;
    float* pre       = (float*)p;            // chunk * HW floats
    long avail = (long)ws_size - (long)(p - (char*)d_ws);
    int chunk = 64;
    if (avail >= (long)C3 * HW * 4)      chunk = C3;
    else if (avail >= (long)192 * HW * 4) chunk = 192;

    // weights -> bf16 (once per call)
    convert_bf16<<<(C3 * DIM + 255) / 256, 256, 0, stream>>>(w_qkv, wqb, C3 * DIM);

    for (int b = 0; b < BB; ++b) {
        const float* xb = x + (long)b * DIM * HW;
        float* outb = out + (long)b * DIM * HW;

        // 0. x -> xT bf16 [16384][192]
        tconv<<<dim3(HW / 64, DIM / 64), 256, 0, stream>>>(xb, xT);
        // 1+2. qkv 1x1 conv (MFMA) + depthwise 3x3, chunked over output channels
        for (int c0 = 0; c0 < C3; c0 += chunk) {
            gemm_mfma<<<dim3(HW / 128, chunk / 64), 256, 0, stream>>>(
                wqb + (long)c0 * DIM, xT, pre, chunk, HW, DIM);
            dwconv3x3<<<dim3(HW / 256, chunk), 256, 0, stream>>>(
                pre, w_dw + (long)c0 * 9, dw + (long)c0 * HW);
        }
        // 3. inverse L2 norms of q,k rows
        rownorm<<<dim3(DIM, 2), 256, 0, stream>>>(dw, norms);
        // 4. QK^T (split-N, atomic accumulate)
        zero_buf<<<36, 256, 0, stream>>>(attn_raw, HEADS * CH * CH);
        attn_partial<<<dim3(HW / 128, HEADS), 256, 0, stream>>>(dw, attn_raw);
        // 5. top-k softmax combine (wave-per-row)
        topk_combine2<<<48, 256, 0, stream>>>(attn_raw, norms, temper, attn_w, Wc);
        // 6. fold proj into [192,192] bf16
        build_m<<<(DIM * DIM + 255) / 256, 256, 0, stream>>>(w_proj, Wc, Mb);
        // 7. v -> vT bf16
        tconv<<<dim3(HW / 64, DIM / 64), 256, 0, stream>>>(dw + (long)2 * DIM * HW, vT);
        // 8. out[b] = M @ v (MFMA)
        gemm_mfma<<<dim3(HW / 128, DIM / 64), 256, 0, stream>>>(
            Mb, vT, outb, DIM, HW, DIM);
    }
}

// Round 6
// 544.765 us; speedup vs baseline: 1.8461x; 1.0645x over previous
//
#include <hip/hip_runtime.h>
#include <math.h>
#include <stdint.h>

// Problem constants
#define BB 4
#define DIM 192
#define HEADS 4
#define CH 48            // DIM/HEADS
#define HW 16384         // 128*128
#define C3 576           // 3*DIM

typedef unsigned short ushort_t;
typedef __attribute__((ext_vector_type(8))) short short8;
typedef __attribute__((ext_vector_type(4))) float floatx4;

__device__ __forceinline__ float bf2f(unsigned int u) {
    union { unsigned int i; float f; } v; v.i = u << 16; return v.f;
}
__device__ __forceinline__ ushort_t f2bf(float f) {  // RNE
    union { float f; unsigned int i; } v; v.f = f;
    unsigned int x = v.i;
    x += 0x7fffu + ((x >> 16) & 1u);
    return (ushort_t)(x >> 16);
}

// ---------------- weights fp32 -> (hi, lo) bf16 pair ----------------
__global__ __launch_bounds__(256) void convert_split(
    const float* __restrict__ in, ushort_t* __restrict__ hi,
    ushort_t* __restrict__ lo, int n)
{
    int i = blockIdx.x * 256 + threadIdx.x;
    if (i < n) {
        float f = in[i];
        ushort_t h = f2bf(f);
        hi[i] = h;
        lo[i] = f2bf(f - bf2f(h));
    }
}

// ---------------- transpose + split-convert: fp32 [192][16384] -> bf16 [16384][192] hi(,lo) ----------------
// grid (16384/64, 192/64), block 256
__global__ __launch_bounds__(256) void tconv(
    const float* __restrict__ in, ushort_t* __restrict__ out_hi,
    ushort_t* __restrict__ out_lo, int wlo)
{
    __shared__ ushort_t th[64][80];
    __shared__ ushort_t tl[64][80];
    int n0 = blockIdx.x * 64, k0 = blockIdx.y * 64;
    int t = threadIdx.x;
#pragma unroll
    for (int i = 0; i < 4; ++i) {
        int kl = (t >> 4) + 16 * i;
        float4 v = *(const float4*)(in + (long)(k0 + kl) * HW + n0 + (t & 15) * 4);
        int nl = (t & 15) * 4;
        ushort_t hx = f2bf(v.x), hy = f2bf(v.y), hz = f2bf(v.z), hw = f2bf(v.w);
        th[nl + 0][kl] = hx; th[nl + 1][kl] = hy;
        th[nl + 2][kl] = hz; th[nl + 3][kl] = hw;
        if (wlo) {
            tl[nl + 0][kl] = f2bf(v.x - bf2f(hx));
            tl[nl + 1][kl] = f2bf(v.y - bf2f(hy));
            tl[nl + 2][kl] = f2bf(v.z - bf2f(hz));
            tl[nl + 3][kl] = f2bf(v.w - bf2f(hw));
        }
    }
    __syncthreads();
#pragma unroll
    for (int i = 0; i < 2; ++i) {
        int nl = t >> 2, seg = (t & 3) + 4 * i;
        *(uint4*)(out_hi + (long)(n0 + nl) * DIM + k0 + seg * 8) = *(uint4*)&th[nl][seg * 8];
        if (wlo)
            *(uint4*)(out_lo + (long)(n0 + nl) * DIM + k0 + seg * 8) = *(uint4*)&tl[nl][seg * 8];
    }
}

// ---------------- register-A MFMA GEMM, K=192 fixed ----------------
// C[M][N] f32 = A[M][192] @ B ( BT[N][192] ), optionally split-bf16 (TERMS=3):
//   C = Ahi@Bhi + Ahi@Blo + Alo@Bhi   (~fp32 accuracy)
// grid (N/128, M/64), block 256 = 4 waves; wave = 32m x 64n; A-frags in VGPRs.
#define BS_STRIDE 104   // shorts per row (96 + 8 pad): 16B-aligned, conflict-free-ish
template<int TERMS>
__global__ __launch_bounds__(256) void gemm_reg(
    const ushort_t* __restrict__ Ahi, const ushort_t* __restrict__ Alo,
    const ushort_t* __restrict__ BThi, const ushort_t* __restrict__ BTlo,
    float* __restrict__ C, int M, int N)
{
    __shared__ ushort_t Bs0[128 * BS_STRIDE];
    __shared__ ushort_t Bs1[128 * BS_STRIDE];
    int t = threadIdx.x;
    int wave = t >> 6, lane = t & 63;
    int l15 = lane & 15, quad = lane >> 4;
    int m0 = blockIdx.y * 64, n0 = blockIdx.x * 128;
    int wm = (wave & 1) * 32, wn = (wave >> 1) * 64;
    floatx4 acc[2][4];
#pragma unroll
    for (int i = 0; i < 2; ++i)
#pragma unroll
        for (int j = 0; j < 4; ++j) acc[i][j] = (floatx4){0.f, 0.f, 0.f, 0.f};

    if (TERMS == 1) {
        // A fragments: 2 mi x 6 k-steps, hi only
        short8 af[2][6];
#pragma unroll
        for (int mi = 0; mi < 2; ++mi)
#pragma unroll
            for (int k0 = 0; k0 < 6; ++k0)
                af[mi][k0] = *(const short8*)(Ahi
                    + (long)(m0 + wm + mi * 16 + l15) * 192 + k0 * 32 + quad * 8);
        // stage all of B: Bs0 = cols 0..95, Bs1 = cols 96..191
        for (int i = t; i < 3072; i += 256) {
            int r = i / 24, seg = i % 24;
            uint4 v = *(const uint4*)(BThi + (long)(n0 + r) * 192 + seg * 8);
            ushort_t* dst = (seg < 12) ? &Bs0[r * BS_STRIDE + seg * 8]
                                       : &Bs1[r * BS_STRIDE + (seg - 12) * 8];
            *(uint4*)dst = v;
        }
        __syncthreads();
#pragma unroll
        for (int k0 = 0; k0 < 6; ++k0) {
            int ks = k0 * 32 + quad * 8;
            const ushort_t* buf = (ks < 96) ? Bs0 : Bs1;
            int col = ks & 95;   // ks<96 ? ks : ks-96 (96=0b1100000; ks<192 so &95 works for both ranges? no)
            col = (ks < 96) ? ks : ks - 96;
            short8 bf[4];
#pragma unroll
            for (int ni = 0; ni < 4; ++ni)
                bf[ni] = *(const short8*)&buf[(wn + ni * 16 + l15) * BS_STRIDE + col];
#pragma unroll
            for (int mi = 0; mi < 2; ++mi)
#pragma unroll
                for (int ni = 0; ni < 4; ++ni)
                    acc[mi][ni] = __builtin_amdgcn_mfma_f32_16x16x32_bf16(
                        af[mi][k0], bf[ni], acc[mi][ni], 0, 0, 0);
        }
    } else {
        // TERMS == 3: two K-halves of 96; per half stage Bhi->Bs0, Blo->Bs1
#pragma unroll
        for (int kh = 0; kh < 2; ++kh) {
            short8 ah[2][3], al[2][3];
#pragma unroll
            for (int mi = 0; mi < 2; ++mi)
#pragma unroll
                for (int k0 = 0; k0 < 3; ++k0) {
                    long off = (long)(m0 + wm + mi * 16 + l15) * 192
                             + kh * 96 + k0 * 32 + quad * 8;
                    ah[mi][k0] = *(const short8*)(Ahi + off);
                    al[mi][k0] = *(const short8*)(Alo + off);
                }
            if (kh) __syncthreads();   // protect previous half's reads
            for (int i = t; i < 1536; i += 256) {
                int r = i / 12, seg = i % 12;
                long goff = (long)(n0 + r) * 192 + kh * 96 + seg * 8;
                *(uint4*)&Bs0[r * BS_STRIDE + seg * 8] = *(const uint4*)(BThi + goff);
                *(uint4*)&Bs1[r * BS_STRIDE + seg * 8] = *(const uint4*)(BTlo + goff);
            }
            __syncthreads();
#pragma unroll
            for (int k0 = 0; k0 < 3; ++k0) {
                int col = k0 * 32 + quad * 8;
                short8 bh[4], bl[4];
#pragma unroll
                for (int ni = 0; ni < 4; ++ni) {
                    bh[ni] = *(const short8*)&Bs0[(wn + ni * 16 + l15) * BS_STRIDE + col];
                    bl[ni] = *(const short8*)&Bs1[(wn + ni * 16 + l15) * BS_STRIDE + col];
                }
#pragma unroll
                for (int mi = 0; mi < 2; ++mi)
#pragma unroll
                    for (int ni = 0; ni < 4; ++ni) {
                        acc[mi][ni] = __builtin_amdgcn_mfma_f32_16x16x32_bf16(
                            ah[mi][k0], bh[ni], acc[mi][ni], 0, 0, 0);
                        acc[mi][ni] = __builtin_amdgcn_mfma_f32_16x16x32_bf16(
                            ah[mi][k0], bl[ni], acc[mi][ni], 0, 0, 0);
                        acc[mi][ni] = __builtin_amdgcn_mfma_f32_16x16x32_bf16(
                            al[mi][k0], bh[ni], acc[mi][ni], 0, 0, 0);
                    }
            }
        }
    }
    // C/D layout: col = lane&15, row = quad*4 + reg
#pragma unroll
    for (int mi = 0; mi < 2; ++mi)
#pragma unroll
        for (int ni = 0; ni < 4; ++ni) {
            long base = (long)(m0 + wm + mi * 16 + quad * 4) * N + n0 + wn + ni * 16 + l15;
#pragma unroll
            for (int r = 0; r < 4; ++r)
                C[base + (long)r * N] = acc[mi][ni][r];
        }
}

// ---------------- Depthwise 3x3, pad 1 — LDS tile, 4 outputs/thread ----------------
// block 256: computes 8 rows x 128 cols of one channel. grid (16, chunk)
__global__ __launch_bounds__(256) void dwconv3x3_lds(
    const float* __restrict__ in, const float* __restrict__ w, float* __restrict__ out)
{
    __shared__ float tile[10][132];
    int c = blockIdx.y;
    int y0 = blockIdx.x * 8;
    long base = (long)c * HW;
    const float* wc = w + c * 9;
    float wf[9];
#pragma unroll
    for (int i = 0; i < 9; ++i) wf[i] = wc[i];
    int t = threadIdx.x;
    if (t < 10) { tile[t][0] = 0.f; tile[t][129] = 0.f; }
    for (int i = t; i < 320; i += 256) {
        int r = i >> 5, c4 = (i & 31) * 4;
        int gy = y0 - 1 + r;
        float4 v = {0.f, 0.f, 0.f, 0.f};
        if (gy >= 0 && gy < 128) v = *(const float4*)(in + base + gy * 128 + c4);
        tile[r][1 + c4] = v.x; tile[r][2 + c4] = v.y;
        tile[r][3 + c4] = v.z; tile[r][4 + c4] = v.w;
    }
    __syncthreads();
    int yl = t >> 5, xl = (t & 31) * 4;
    float s0 = 0.f, s1 = 0.f, s2 = 0.f, s3 = 0.f;
#pragma unroll
    for (int r = 0; r < 3; ++r) {
        float c0v = tile[yl + r][xl + 0], c1v = tile[yl + r][xl + 1];
        float c2v = tile[yl + r][xl + 2], c3v = tile[yl + r][xl + 3];
        float c4v = tile[yl + r][xl + 4], c5v = tile[yl + r][xl + 5];
        float w0 = wf[r * 3], w1 = wf[r * 3 + 1], w2 = wf[r * 3 + 2];
        s0 += w0 * c0v + w1 * c1v + w2 * c2v;
        s1 += w0 * c1v + w1 * c2v + w2 * c3v;
        s2 += w0 * c2v + w1 * c3v + w2 * c4v;
        s3 += w0 * c3v + w1 * c4v + w2 * c5v;
    }
    float4 o = {s0, s1, s2, s3};
    *(float4*)(out + base + (y0 + yl) * 128 + xl) = o;
}

// ---------------- Row inverse norms for q (which=0) and k (which=1) ----------------
__global__ __launch_bounds__(256) void rownorm(
    const float* __restrict__ dw, float* __restrict__ norms)
{
    int which = blockIdx.y;
    int r = blockIdx.x;
    const float* p = dw + ((long)which * DIM + r) * HW;
    int t = threadIdx.x;
    float s = 0.f;
#pragma unroll
    for (int i = 0; i < 16; ++i) {
        float4 v = *(const float4*)(p + (t + i * 256) * 4);
        s += v.x * v.x + v.y * v.y + v.z * v.z + v.w * v.w;
    }
    __shared__ float red[256];
    red[t] = s; __syncthreads();
    for (int off = 128; off > 0; off >>= 1) {
        if (t < off) red[t] += red[t + off];
        __syncthreads();
    }
    if (t == 0) {
        float n = sqrtf(red[0]);
        norms[which * DIM + r] = 1.0f / fmaxf(n, 1e-12f);
    }
}

__global__ void zero_buf(float* __restrict__ p, int n) {
    int i = blockIdx.x * 256 + threadIdx.x;
    if (i < n) p[i] = 0.f;
}

// ---------------- attn_raw[h,c,d] += partial QK^T over one 128-wide n-chunk ----------------
__global__ __launch_bounds__(256) void attn_partial(
    const float* __restrict__ dw, float* __restrict__ attn_raw)
{
    int h = blockIdx.y;
    int n0 = blockIdx.x * 128;
    __shared__ float qs[48][132];
    __shared__ float ks[48][132];
    const float* qbase = dw + (long)(h * CH) * HW + n0;
    const float* kbase = dw + (long)(DIM + h * CH) * HW + n0;
    int t = threadIdx.x;
#pragma unroll
    for (int i = 0; i < 6; ++i) {
        int f = t + i * 256;
        int row = f >> 5;
        int c4 = (f & 31) * 4;
        float4 qv = *(const float4*)(qbase + (long)row * HW + c4);
        float4 kv = *(const float4*)(kbase + (long)row * HW + c4);
        *(float4*)&qs[row][c4] = qv;
        *(float4*)&ks[row][c4] = kv;
    }
    __syncthreads();
    int tx = t & 15, ty = t >> 4;
    int c0 = ty * 3, d0 = tx * 3;
    float acc[3][3] = {};
    for (int nv = 0; nv < 32; ++nv) {
        float4 qa[3], kb[3];
#pragma unroll
        for (int i = 0; i < 3; ++i) qa[i] = *(const float4*)&qs[c0 + i][nv * 4];
#pragma unroll
        for (int j = 0; j < 3; ++j) kb[j] = *(const float4*)&ks[d0 + j][nv * 4];
#pragma unroll
        for (int i = 0; i < 3; ++i)
#pragma unroll
            for (int j = 0; j < 3; ++j)
                acc[i][j] += qa[i].x * kb[j].x + qa[i].y * kb[j].y
                           + qa[i].z * kb[j].z + qa[i].w * kb[j].w;
    }
#pragma unroll
    for (int i = 0; i < 3; ++i)
#pragma unroll
        for (int j = 0; j < 3; ++j)
            atomicAdd(&attn_raw[((long)h * CH + c0 + i) * CH + d0 + j], acc[i][j]);
}

// ---------------- top-k softmax combine: one WAVE per row, one lane per element ----------------
__global__ __launch_bounds__(256) void topk_combine2(
    const float* __restrict__ attn_raw, const float* __restrict__ norms,
    const float* __restrict__ temp, const float* __restrict__ attn_w,
    float* __restrict__ Wc)
{
    int wave = threadIdx.x >> 6, lane = threadIdx.x & 63;
    int rid = blockIdx.x * 4 + wave;   // 0..191 = h*48 + c
    int c = rid % CH, h = rid / CH;
    int d = lane;
    float a = -INFINITY;
    if (d < 48)
        a = attn_raw[(long)rid * CH + d] * norms[h * CH + c]
          * norms[DIM + h * CH + d] * temp[h];
    float m = a;
#pragma unroll
    for (int off = 32; off > 0; off >>= 1) m = fmaxf(m, __shfl_xor(m, off, 64));
    float e = (d < 48) ? expf(a - m) : 0.f;
    int rank = 0;
    for (int j = 0; j < 48; ++j) {
        float aj = __shfl(a, j, 64);
        rank += (aj > a) || (aj == a && j < d);
    }
    // k = int(48*rate) in IEEE double: {24, 32, 36, 38} (48*(2/3) rounds UP to 32.0)
    const int kv[4] = {24, 32, 36, 38};
    float s = 0.f;
#pragma unroll
    for (int i = 0; i < 4; ++i) {
        float contrib = (d < 48 && rank < kv[i]) ? e : 0.f;
#pragma unroll
        for (int off = 32; off > 0; off >>= 1) contrib += __shfl_xor(contrib, off, 64);
        s += (rank < kv[i]) ? attn_w[i] / contrib : 0.f;
    }
    if (d < 48) Wc[(long)rid * CH + d] = e * s;
}

// ---------------- M[o, h*48+d] = sum_ch wproj[o, h*48+ch] * Wc[h,ch,d] -> bf16 ----------------
__global__ __launch_bounds__(256) void build_m(
    const float* __restrict__ wproj, const float* __restrict__ Wc,
    ushort_t* __restrict__ Mb)
{
    int idx = blockIdx.x * 256 + threadIdx.x;
    if (idx >= DIM * DIM) return;
    int cg = idx % DIM;
    int o  = idx / DIM;
    int h = cg / CH, d = cg % CH;
    const float* wp = wproj + o * DIM + h * CH;
    const float* wcc = Wc + (long)h * CH * CH + d;
    float s = 0.f;
#pragma unroll
    for (int ch = 0; ch < CH; ++ch) s += wp[ch] * wcc[ch * CH];
    Mb[idx] = f2bf(s);
}

extern "C" void kernel_launch(void* const* d_in, const int* in_sizes, int n_in,
                              void* d_out, int out_size, void* d_ws, size_t ws_size,
                              hipStream_t stream) {
    const float* x      = (const float*)d_in[0];   // [4,192,128,128]
    const float* w_qkv  = (const float*)d_in[1];   // [576,192]
    const float* w_dw   = (const float*)d_in[2];   // [576,9]
    const float* w_proj = (const float*)d_in[3];   // [192,192]
    const float* temper = (const float*)d_in[4];   // [4]
    const float* attn_w = (const float*)d_in[5];   // [4]
    float* out = (float*)d_out;                    // [4,192,128,128]

    // Workspace layout (per-batch reuse); all offsets 16B-aligned.
    char* p = (char*)d_ws;
    float* dw        = (float*)p;      p += (long)C3 * HW * 4;      // 37.75 MB
    ushort_t* xT_hi  = (ushort_t*)p;   p += (long)HW * DIM * 2;     // 6.29 MB
    ushort_t* xT_lo  = (ushort_t*)p;   p += (long)HW * DIM * 2;     // 6.29 MB
    ushort_t* wq_hi  = (ushort_t*)p;   p += (long)C3 * DIM * 2;
    ushort_t* wq_lo  = (ushort_t*)p;   p += (long)C3 * DIM * 2;
    float* norms     = (float*)p;      p += 2048;
    float* attn_raw  = (float*)p;      p += 9216 * 4;
    float* Wc        = (float*)p;      p += 9216 * 4;
    ushort_t* Mb     = (ushort_t*)p;   p += (long)DIM * DIM * 2;
    float* pre       = (float*)p;      // chunk * HW floats
    long avail = (long)ws_size - (long)(p - (char*)d_ws);
    int chunk = 64;
    if (avail >= (long)C3 * HW * 4)       chunk = C3;   // 37.75 MB
    else if (avail >= (long)192 * HW * 4) chunk = 192;  // 12.6 MB

    // weights -> split bf16 (once per call)
    convert_split<<<(C3 * DIM + 255) / 256, 256, 0, stream>>>(
        w_qkv, wq_hi, wq_lo, C3 * DIM);

    for (int b = 0; b < BB; ++b) {
        const float* xb = x + (long)b * DIM * HW;
        float* outb = out + (long)b * DIM * HW;

        // 0. x -> xT hi/lo bf16 [16384][192]
        tconv<<<dim3(HW / 64, DIM / 64), 256, 0, stream>>>(xb, xT_hi, xT_lo, 1);
        // 1+2. qkv 1x1 conv (split-bf16 MFMA, ~fp32-accurate) + depthwise 3x3
        for (int c0 = 0; c0 < C3; c0 += chunk) {
            gemm_reg<3><<<dim3(HW / 128, chunk / 64), 256, 0, stream>>>(
                wq_hi + (long)c0 * DIM, wq_lo + (long)c0 * DIM,
                xT_hi, xT_lo, pre, chunk, HW);
            dwconv3x3_lds<<<dim3(16, chunk), 256, 0, stream>>>(
                pre, w_dw + (long)c0 * 9, dw + (long)c0 * HW);
        }
        // 3. inverse L2 norms of q,k rows
        rownorm<<<dim3(DIM, 2), 256, 0, stream>>>(dw, norms);
        // 4. QK^T (split-N, atomic accumulate, fp32)
        zero_buf<<<36, 256, 0, stream>>>(attn_raw, HEADS * CH * CH);
        attn_partial<<<dim3(HW / 128, HEADS), 256, 0, stream>>>(dw, attn_raw);
        // 5. top-k softmax combine (wave-per-row)
        topk_combine2<<<48, 256, 0, stream>>>(attn_raw, norms, temper, attn_w, Wc);
        // 6. fold proj into [192,192] bf16
        build_m<<<(DIM * DIM + 255) / 256, 256, 0, stream>>>(w_proj, Wc, Mb);
        // 7. v -> vT bf16 (hi only; reuse xT_hi)
        tconv<<<dim3(HW / 64, DIM / 64), 256, 0, stream>>>(
            dw + (long)2 * DIM * HW, xT_hi, xT_lo, 0);
        // 8. out[b] = M @ v (MFMA, single term)
        gemm_reg<1><<<dim3(HW / 128, DIM / 64), 256, 0, stream>>>(
            Mb, Mb, xT_hi, xT_hi, outb, DIM, HW);
    }
}

// Round 7
// 435.980 us; speedup vs baseline: 2.3067x; 1.2495x over previous
//
#include <hip/hip_runtime.h>
#include <math.h>
#include <stdint.h>

// Problem constants
#define BB 4
#define DIM 192
#define HEADS 4
#define CH 48            // DIM/HEADS
#define HW 16384         // 128*128
#define C3 576           // 3*DIM

typedef unsigned short ushort_t;
typedef __attribute__((ext_vector_type(8))) short short8;
typedef __attribute__((ext_vector_type(4))) float floatx4;

__device__ __forceinline__ float bf2f(unsigned int u) {
    union { unsigned int i; float f; } v; v.i = u << 16; return v.f;
}
__device__ __forceinline__ ushort_t f2bf(float f) {  // RNE
    union { float f; unsigned int i; } v; v.f = f;
    unsigned int x = v.i;
    x += 0x7fffu + ((x >> 16) & 1u);
    return (ushort_t)(x >> 16);
}

// ---------------- zero normsq + attn_raw (all batches, one launch) ----------------
__global__ __launch_bounds__(256) void zero_init(float* __restrict__ p, int n) {
    int i = blockIdx.x * 256 + threadIdx.x;
    if (i < n) p[i] = 0.f;
}

// ---------------- weights fp32 -> (hi, lo) bf16 pair ----------------
__global__ __launch_bounds__(256) void convert_split(
    const float* __restrict__ in, ushort_t* __restrict__ hi,
    ushort_t* __restrict__ lo, int n)
{
    int i = blockIdx.x * 256 + threadIdx.x;
    if (i < n) {
        float f = in[i];
        ushort_t h = f2bf(f);
        hi[i] = h;
        lo[i] = f2bf(f - bf2f(h));
    }
}

// ---------------- transpose + split-convert: fp32 [192][16384] -> bf16 [16384][192] hi(,lo) ----------------
// grid (HW/64, DIM/64, BB), block 256. inStride/outStride: per-z element offsets.
__global__ __launch_bounds__(256) void tconv(
    const float* __restrict__ in, ushort_t* __restrict__ out_hi,
    ushort_t* __restrict__ out_lo, int wlo, long inStride)
{
    int z = blockIdx.z;
    in += (long)z * inStride;
    out_hi += (long)z * HW * DIM;
    if (wlo) out_lo += (long)z * HW * DIM;
    __shared__ ushort_t th[64][80];
    __shared__ ushort_t tl[64][80];
    int n0 = blockIdx.x * 64, k0 = blockIdx.y * 64;
    int t = threadIdx.x;
#pragma unroll
    for (int i = 0; i < 4; ++i) {
        int kl = (t >> 4) + 16 * i;
        float4 v = *(const float4*)(in + (long)(k0 + kl) * HW + n0 + (t & 15) * 4);
        int nl = (t & 15) * 4;
        ushort_t hx = f2bf(v.x), hy = f2bf(v.y), hz = f2bf(v.z), hw = f2bf(v.w);
        th[nl + 0][kl] = hx; th[nl + 1][kl] = hy;
        th[nl + 2][kl] = hz; th[nl + 3][kl] = hw;
        if (wlo) {
            tl[nl + 0][kl] = f2bf(v.x - bf2f(hx));
            tl[nl + 1][kl] = f2bf(v.y - bf2f(hy));
            tl[nl + 2][kl] = f2bf(v.z - bf2f(hz));
            tl[nl + 3][kl] = f2bf(v.w - bf2f(hw));
        }
    }
    __syncthreads();
#pragma unroll
    for (int i = 0; i < 2; ++i) {
        int nl = t >> 2, seg = (t & 3) + 4 * i;
        *(uint4*)(out_hi + (long)(n0 + nl) * DIM + k0 + seg * 8) = *(uint4*)&th[nl][seg * 8];
        if (wlo)
            *(uint4*)(out_lo + (long)(n0 + nl) * DIM + k0 + seg * 8) = *(uint4*)&tl[nl][seg * 8];
    }
}

// ---------------- register-A MFMA GEMM, K=192 fixed, batched over z ----------------
// C[M][N] f32 = A[M][192] @ B ( BT[N][192] ); TERMS=3: Ahi@Bhi + Ahi@Blo + Alo@Bhi
// grid (N/128, M/64, BB), block 256 = 4 waves; wave = 32m x 64n; A-frags in VGPRs.
#define BS_STRIDE 104   // shorts per row (96 + 8 pad): 16B-aligned
template<int TERMS>
__global__ __launch_bounds__(256) void gemm_reg(
    const ushort_t* __restrict__ Ahi, const ushort_t* __restrict__ Alo,
    const ushort_t* __restrict__ BThi, const ushort_t* __restrict__ BTlo,
    float* __restrict__ C, int M, int N,
    long strideA, long strideB, long strideC)
{
    int z = blockIdx.z;
    Ahi += z * strideA; Alo += z * strideA;
    BThi += z * strideB; BTlo += z * strideB;
    C += z * strideC;
    __shared__ ushort_t Bs0[128 * BS_STRIDE];
    __shared__ ushort_t Bs1[128 * BS_STRIDE];
    int t = threadIdx.x;
    int wave = t >> 6, lane = t & 63;
    int l15 = lane & 15, quad = lane >> 4;
    int m0 = blockIdx.y * 64, n0 = blockIdx.x * 128;
    int wm = (wave & 1) * 32, wn = (wave >> 1) * 64;
    floatx4 acc[2][4];
#pragma unroll
    for (int i = 0; i < 2; ++i)
#pragma unroll
        for (int j = 0; j < 4; ++j) acc[i][j] = (floatx4){0.f, 0.f, 0.f, 0.f};

    if (TERMS == 1) {
        short8 af[2][6];
#pragma unroll
        for (int mi = 0; mi < 2; ++mi)
#pragma unroll
            for (int k0 = 0; k0 < 6; ++k0)
                af[mi][k0] = *(const short8*)(Ahi
                    + (long)(m0 + wm + mi * 16 + l15) * 192 + k0 * 32 + quad * 8);
        for (int i = t; i < 3072; i += 256) {
            int r = i / 24, seg = i % 24;
            uint4 v = *(const uint4*)(BThi + (long)(n0 + r) * 192 + seg * 8);
            ushort_t* dst = (seg < 12) ? &Bs0[r * BS_STRIDE + seg * 8]
                                       : &Bs1[r * BS_STRIDE + (seg - 12) * 8];
            *(uint4*)dst = v;
        }
        __syncthreads();
#pragma unroll
        for (int k0 = 0; k0 < 6; ++k0) {
            int ks = k0 * 32 + quad * 8;
            const ushort_t* buf = (ks < 96) ? Bs0 : Bs1;
            int col = (ks < 96) ? ks : ks - 96;
            short8 bf[4];
#pragma unroll
            for (int ni = 0; ni < 4; ++ni)
                bf[ni] = *(const short8*)&buf[(wn + ni * 16 + l15) * BS_STRIDE + col];
#pragma unroll
            for (int mi = 0; mi < 2; ++mi)
#pragma unroll
                for (int ni = 0; ni < 4; ++ni)
                    acc[mi][ni] = __builtin_amdgcn_mfma_f32_16x16x32_bf16(
                        af[mi][k0], bf[ni], acc[mi][ni], 0, 0, 0);
        }
    } else {
#pragma unroll
        for (int kh = 0; kh < 2; ++kh) {
            short8 ah[2][3], al[2][3];
#pragma unroll
            for (int mi = 0; mi < 2; ++mi)
#pragma unroll
                for (int k0 = 0; k0 < 3; ++k0) {
                    long off = (long)(m0 + wm + mi * 16 + l15) * 192
                             + kh * 96 + k0 * 32 + quad * 8;
                    ah[mi][k0] = *(const short8*)(Ahi + off);
                    al[mi][k0] = *(const short8*)(Alo + off);
                }
            if (kh) __syncthreads();
            for (int i = t; i < 1536; i += 256) {
                int r = i / 12, seg = i % 12;
                long goff = (long)(n0 + r) * 192 + kh * 96 + seg * 8;
                *(uint4*)&Bs0[r * BS_STRIDE + seg * 8] = *(const uint4*)(BThi + goff);
                *(uint4*)&Bs1[r * BS_STRIDE + seg * 8] = *(const uint4*)(BTlo + goff);
            }
            __syncthreads();
#pragma unroll
            for (int k0 = 0; k0 < 3; ++k0) {
                int col = k0 * 32 + quad * 8;
                short8 bh[4], bl[4];
#pragma unroll
                for (int ni = 0; ni < 4; ++ni) {
                    bh[ni] = *(const short8*)&Bs0[(wn + ni * 16 + l15) * BS_STRIDE + col];
                    bl[ni] = *(const short8*)&Bs1[(wn + ni * 16 + l15) * BS_STRIDE + col];
                }
#pragma unroll
                for (int mi = 0; mi < 2; ++mi)
#pragma unroll
                    for (int ni = 0; ni < 4; ++ni) {
                        acc[mi][ni] = __builtin_amdgcn_mfma_f32_16x16x32_bf16(
                            ah[mi][k0], bh[ni], acc[mi][ni], 0, 0, 0);
                        acc[mi][ni] = __builtin_amdgcn_mfma_f32_16x16x32_bf16(
                            ah[mi][k0], bl[ni], acc[mi][ni], 0, 0, 0);
                        acc[mi][ni] = __builtin_amdgcn_mfma_f32_16x16x32_bf16(
                            al[mi][k0], bh[ni], acc[mi][ni], 0, 0, 0);
                    }
            }
        }
    }
    // C/D layout: col = lane&15, row = quad*4 + reg
#pragma unroll
    for (int mi = 0; mi < 2; ++mi)
#pragma unroll
        for (int ni = 0; ni < 4; ++ni) {
            long base = (long)(m0 + wm + mi * 16 + quad * 4) * N + n0 + wn + ni * 16 + l15;
#pragma unroll
            for (int r = 0; r < 4; ++r)
                C[base + (long)r * N] = acc[mi][ni][r];
        }
}

// ---------------- Depthwise 3x3 + fused sum-of-squares (for q,k channels) ----------------
// grid (16, chunk, BB), block 256: 8 rows x 128 cols of one channel.
__global__ __launch_bounds__(256) void dwconv3x3_lds(
    const float* __restrict__ in, const float* __restrict__ w,
    float* __restrict__ out, float* __restrict__ normsq,
    int c0, int chunk)
{
    __shared__ float tile[10][132];
    int z = blockIdx.z;
    int cl = blockIdx.y;              // local channel in chunk
    int gc = c0 + cl;                 // global channel 0..575
    in  += (long)z * chunk * HW + (long)cl * HW;
    out += (long)z * C3 * HW + (long)gc * HW;
    int y0 = blockIdx.x * 8;
    const float* wc = w + gc * 9;
    float wf[9];
#pragma unroll
    for (int i = 0; i < 9; ++i) wf[i] = wc[i];
    int t = threadIdx.x;
    if (t < 10) { tile[t][0] = 0.f; tile[t][129] = 0.f; }
    for (int i = t; i < 320; i += 256) {
        int r = i >> 5, c4 = (i & 31) * 4;
        int gy = y0 - 1 + r;
        float4 v = {0.f, 0.f, 0.f, 0.f};
        if (gy >= 0 && gy < 128) v = *(const float4*)(in + gy * 128 + c4);
        tile[r][1 + c4] = v.x; tile[r][2 + c4] = v.y;
        tile[r][3 + c4] = v.z; tile[r][4 + c4] = v.w;
    }
    __syncthreads();
    int yl = t >> 5, xl = (t & 31) * 4;
    float s0 = 0.f, s1 = 0.f, s2 = 0.f, s3 = 0.f;
#pragma unroll
    for (int r = 0; r < 3; ++r) {
        float c0v = tile[yl + r][xl + 0], c1v = tile[yl + r][xl + 1];
        float c2v = tile[yl + r][xl + 2], c3v = tile[yl + r][xl + 3];
        float c4v = tile[yl + r][xl + 4], c5v = tile[yl + r][xl + 5];
        float w0 = wf[r * 3], w1 = wf[r * 3 + 1], w2 = wf[r * 3 + 2];
        s0 += w0 * c0v + w1 * c1v + w2 * c2v;
        s1 += w0 * c1v + w1 * c2v + w2 * c3v;
        s2 += w0 * c2v + w1 * c3v + w2 * c4v;
        s3 += w0 * c3v + w1 * c4v + w2 * c5v;
    }
    float4 o = {s0, s1, s2, s3};
    *(float4*)(out + (y0 + yl) * 128 + xl) = o;
    if (gc < 2 * DIM) {   // q or k channel: accumulate sum of squares
        __syncthreads();                 // done reading tile; reuse as reduction buf
        float* red = (float*)tile;
        red[t] = s0 * s0 + s1 * s1 + s2 * s2 + s3 * s3;
        __syncthreads();
        for (int off = 128; off > 0; off >>= 1) {
            if (t < off) red[t] += red[t + off];
            __syncthreads();
        }
        if (t == 0) atomicAdd(&normsq[z * 512 + gc], red[0]);
    }
}

// ---------------- attn_raw[z,h,c,d] += partial QK^T over one 128-wide n-chunk ----------------
__global__ __launch_bounds__(256) void attn_partial(
    const float* __restrict__ dw, float* __restrict__ attn_raw)
{
    int z = blockIdx.z;
    int h = blockIdx.y;
    int n0 = blockIdx.x * 128;
    dw += (long)z * C3 * HW;
    attn_raw += (long)z * 9216;
    __shared__ float qs[48][132];
    __shared__ float ks[48][132];
    const float* qbase = dw + (long)(h * CH) * HW + n0;
    const float* kbase = dw + (long)(DIM + h * CH) * HW + n0;
    int t = threadIdx.x;
#pragma unroll
    for (int i = 0; i < 6; ++i) {
        int f = t + i * 256;
        int row = f >> 5;
        int c4 = (f & 31) * 4;
        float4 qv = *(const float4*)(qbase + (long)row * HW + c4);
        float4 kv = *(const float4*)(kbase + (long)row * HW + c4);
        *(float4*)&qs[row][c4] = qv;
        *(float4*)&ks[row][c4] = kv;
    }
    __syncthreads();
    int tx = t & 15, ty = t >> 4;
    int c0 = ty * 3, d0 = tx * 3;
    float acc[3][3] = {};
    for (int nv = 0; nv < 32; ++nv) {
        float4 qa[3], kb[3];
#pragma unroll
        for (int i = 0; i < 3; ++i) qa[i] = *(const float4*)&qs[c0 + i][nv * 4];
#pragma unroll
        for (int j = 0; j < 3; ++j) kb[j] = *(const float4*)&ks[d0 + j][nv * 4];
#pragma unroll
        for (int i = 0; i < 3; ++i)
#pragma unroll
            for (int j = 0; j < 3; ++j)
                acc[i][j] += qa[i].x * kb[j].x + qa[i].y * kb[j].y
                           + qa[i].z * kb[j].z + qa[i].w * kb[j].w;
    }
#pragma unroll
    for (int i = 0; i < 3; ++i)
#pragma unroll
        for (int j = 0; j < 3; ++j)
            atomicAdd(&attn_raw[(long)(c0 + i) * CH + d0 + j + (long)h * CH * CH], acc[i][j]);
}

// ---------------- top-k softmax combine: one WAVE per row; norms from fused sumsq ----------------
// grid (48, BB), block 256 (4 waves = 4 rows)
__global__ __launch_bounds__(256) void topk_combine2(
    const float* __restrict__ attn_raw, const float* __restrict__ normsq,
    const float* __restrict__ temp, const float* __restrict__ attn_w,
    float* __restrict__ Wc)
{
    int z = blockIdx.y;
    int wave = threadIdx.x >> 6, lane = threadIdx.x & 63;
    int rid = blockIdx.x * 4 + wave;   // 0..191 = h*48 + c
    int c = rid % CH, h = rid / CH;
    int d = lane;
    float a = -INFINITY;
    if (d < 48) {
        float invq = 1.0f / fmaxf(sqrtf(normsq[z * 512 + h * CH + c]), 1e-12f);
        float invk = 1.0f / fmaxf(sqrtf(normsq[z * 512 + DIM + h * CH + d]), 1e-12f);
        a = attn_raw[(long)z * 9216 + (long)rid * CH + d] * invq * invk * temp[h];
    }
    float m = a;
#pragma unroll
    for (int off = 32; off > 0; off >>= 1) m = fmaxf(m, __shfl_xor(m, off, 64));
    float e = (d < 48) ? expf(a - m) : 0.f;
    int rank = 0;
    for (int j = 0; j < 48; ++j) {
        float aj = __shfl(a, j, 64);
        rank += (aj > a) || (aj == a && j < d);
    }
    // k = int(48*rate) in IEEE double: {24, 32, 36, 38} (48*(2/3) rounds UP to 32.0)
    const int kv[4] = {24, 32, 36, 38};
    float s = 0.f;
#pragma unroll
    for (int i = 0; i < 4; ++i) {
        float contrib = (d < 48 && rank < kv[i]) ? e : 0.f;
#pragma unroll
        for (int off = 32; off > 0; off >>= 1) contrib += __shfl_xor(contrib, off, 64);
        s += (rank < kv[i]) ? attn_w[i] / contrib : 0.f;
    }
    if (d < 48) Wc[(long)z * 9216 + (long)rid * CH + d] = e * s;
}

// ---------------- M[z][o, h*48+d] = sum_ch wproj[o, h*48+ch] * Wc[z][h,ch,d] -> bf16 ----------------
__global__ __launch_bounds__(256) void build_m(
    const float* __restrict__ wproj, const float* __restrict__ Wc,
    ushort_t* __restrict__ Mb)
{
    int z = blockIdx.y;
    int idx = blockIdx.x * 256 + threadIdx.x;
    if (idx >= DIM * DIM) return;
    int cg = idx % DIM;
    int o  = idx / DIM;
    int h = cg / CH, d = cg % CH;
    const float* wp = wproj + o * DIM + h * CH;
    const float* wcc = Wc + (long)z * 9216 + (long)h * CH * CH + d;
    float s = 0.f;
#pragma unroll
    for (int ch = 0; ch < CH; ++ch) s += wp[ch] * wcc[ch * CH];
    Mb[(long)z * DIM * DIM + idx] = f2bf(s);
}

extern "C" void kernel_launch(void* const* d_in, const int* in_sizes, int n_in,
                              void* d_out, int out_size, void* d_ws, size_t ws_size,
                              hipStream_t stream) {
    const float* x      = (const float*)d_in[0];   // [4,192,128,128]
    const float* w_qkv  = (const float*)d_in[1];   // [576,192]
    const float* w_dw   = (const float*)d_in[2];   // [576,9]
    const float* w_proj = (const float*)d_in[3];   // [192,192]
    const float* temper = (const float*)d_in[4];   // [4]
    const float* attn_w = (const float*)d_in[5];   // [4]
    float* out = (float*)d_out;                    // [4,192,128,128]

    // Workspace (ws = 256 MiB per rocprof fill evidence). All-batch layout:
    char* p = (char*)d_ws;
    float* dw        = (float*)p;      p += (long)BB * C3 * HW * 4;   // 151.0 MB
    ushort_t* xT_hi  = (ushort_t*)p;   p += (long)BB * HW * DIM * 2;  // 25.2 MB
    ushort_t* xT_lo  = (ushort_t*)p;   p += (long)BB * HW * DIM * 2;  // 25.2 MB
    ushort_t* wq_hi  = (ushort_t*)p;   p += (long)C3 * DIM * 2;
    ushort_t* wq_lo  = (ushort_t*)p;   p += (long)C3 * DIM * 2;
    float* normsq    = (float*)p;      p += (long)BB * 512 * 4;       // sumsq, q+k channels
    float* attn_raw  = (float*)p;      p += (long)BB * 9216 * 4;
    float* Wc        = (float*)p;      p += (long)BB * 9216 * 4;
    ushort_t* Mb     = (ushort_t*)p;   p += (long)BB * DIM * DIM * 2;
    float* pre       = (float*)p;      // BB * chunk * HW floats
    long avail = (long)ws_size - (long)(p - (char*)d_ws);
    int chunk = 64;                                         // 16.8 MB
    if (avail >= (long)BB * 192 * HW * 4) chunk = 192;      // 50.3 MB

    // 0a. zero normsq + attn_raw (one launch, all batches)
    zero_init<<<(BB * 512 + BB * 9216 + 255) / 256, 256, 0, stream>>>(
        normsq, BB * 512 + BB * 9216);   // contiguous: normsq then attn_raw
    // 0b. weights -> split bf16
    convert_split<<<(C3 * DIM + 255) / 256, 256, 0, stream>>>(
        w_qkv, wq_hi, wq_lo, C3 * DIM);
    // 0c. x -> xT hi/lo bf16, all batches
    tconv<<<dim3(HW / 64, DIM / 64, BB), 256, 0, stream>>>(
        x, xT_hi, xT_lo, 1, (long)DIM * HW);

    // 1+2. qkv 1x1 (split-bf16 MFMA) + dwconv3x3 (+fused q/k sumsq), chunked over channels
    for (int c0 = 0; c0 < C3; c0 += chunk) {
        gemm_reg<3><<<dim3(HW / 128, chunk / 64, BB), 256, 0, stream>>>(
            wq_hi + (long)c0 * DIM, wq_lo + (long)c0 * DIM, xT_hi, xT_lo,
            pre, chunk, HW, 0L, (long)HW * DIM, (long)chunk * HW);
        dwconv3x3_lds<<<dim3(16, chunk, BB), 256, 0, stream>>>(
            pre, w_dw, dw, normsq, c0, chunk);
    }
    // 3. QK^T (split-N, atomic accumulate, fp32)
    attn_partial<<<dim3(HW / 128, HEADS, BB), 256, 0, stream>>>(dw, attn_raw);
    // 4. top-k softmax combine (wave-per-row; norms inline from sumsq)
    topk_combine2<<<dim3(48, BB), 256, 0, stream>>>(
        attn_raw, normsq, temper, attn_w, Wc);
    // 5. fold proj into per-batch [192,192] bf16
    build_m<<<dim3((DIM * DIM + 255) / 256, BB), 256, 0, stream>>>(w_proj, Wc, Mb);
    // 6. v -> vT bf16 (hi only; reuse xT_hi), all batches
    tconv<<<dim3(HW / 64, DIM / 64, BB), 256, 0, stream>>>(
        dw + (long)2 * DIM * HW, xT_hi, xT_lo, 0, (long)C3 * HW);
    // 7. out = M @ v (MFMA, single term), all batches
    gemm_reg<1><<<dim3(HW / 128, DIM / 64, BB), 256, 0, stream>>>(
        Mb, Mb, xT_hi, xT_hi, out, DIM, HW,
        (long)DIM * DIM, (long)HW * DIM, (long)DIM * HW);
}

// Round 8
// 387.877 us; speedup vs baseline: 2.5928x; 1.1240x over previous
//
#include <hip/hip_runtime.h>
#include <math.h>
#include <stdint.h>

// Problem constants
#define BB 4
#define DIM 192
#define HEADS 4
#define CH 48            // DIM/HEADS
#define HW 16384         // 128*128
#define C3 576           // 3*DIM
#define NCHUNK 64        // attention n-chunks (chunk = 256 cols)

typedef unsigned short ushort_t;
typedef __attribute__((ext_vector_type(8))) short short8;
typedef __attribute__((ext_vector_type(4))) float floatx4;

__device__ __forceinline__ float bf2f(unsigned int u) {
    union { unsigned int i; float f; } v; v.i = u << 16; return v.f;
}
__device__ __forceinline__ ushort_t f2bf(float f) {  // RNE
    union { float f; unsigned int i; } v; v.f = f;
    unsigned int x = v.i;
    x += 0x7fffu + ((x >> 16) & 1u);
    return (ushort_t)(x >> 16);
}

__global__ __launch_bounds__(256) void zero_init(float* __restrict__ p, int n) {
    int i = blockIdx.x * 256 + threadIdx.x;
    if (i < n) p[i] = 0.f;
}

// ---------------- weights fp32 -> (hi, lo) bf16 pair ----------------
__global__ __launch_bounds__(256) void convert_split(
    const float* __restrict__ in, ushort_t* __restrict__ hi,
    ushort_t* __restrict__ lo, int n)
{
    int i = blockIdx.x * 256 + threadIdx.x;
    if (i < n) {
        float f = in[i];
        ushort_t h = f2bf(f);
        hi[i] = h;
        lo[i] = f2bf(f - bf2f(h));
    }
}

// ---------------- transpose + split-convert: fp32 [192][16384] -> bf16 [16384][192] hi(,lo) ----------------
__global__ __launch_bounds__(256) void tconv(
    const float* __restrict__ in, ushort_t* __restrict__ out_hi,
    ushort_t* __restrict__ out_lo, int wlo, long inStride)
{
    int z = blockIdx.z;
    in += (long)z * inStride;
    out_hi += (long)z * HW * DIM;
    if (wlo) out_lo += (long)z * HW * DIM;
    __shared__ ushort_t th[64][80];
    __shared__ ushort_t tl[64][80];
    int n0 = blockIdx.x * 64, k0 = blockIdx.y * 64;
    int t = threadIdx.x;
#pragma unroll
    for (int i = 0; i < 4; ++i) {
        int kl = (t >> 4) + 16 * i;
        float4 v = *(const float4*)(in + (long)(k0 + kl) * HW + n0 + (t & 15) * 4);
        int nl = (t & 15) * 4;
        ushort_t hx = f2bf(v.x), hy = f2bf(v.y), hz = f2bf(v.z), hw = f2bf(v.w);
        th[nl + 0][kl] = hx; th[nl + 1][kl] = hy;
        th[nl + 2][kl] = hz; th[nl + 3][kl] = hw;
        if (wlo) {
            tl[nl + 0][kl] = f2bf(v.x - bf2f(hx));
            tl[nl + 1][kl] = f2bf(v.y - bf2f(hy));
            tl[nl + 2][kl] = f2bf(v.z - bf2f(hz));
            tl[nl + 3][kl] = f2bf(v.w - bf2f(hw));
        }
    }
    __syncthreads();
#pragma unroll
    for (int i = 0; i < 2; ++i) {
        int nl = t >> 2, seg = (t & 3) + 4 * i;
        *(uint4*)(out_hi + (long)(n0 + nl) * DIM + k0 + seg * 8) = *(uint4*)&th[nl][seg * 8];
        if (wlo)
            *(uint4*)(out_lo + (long)(n0 + nl) * DIM + k0 + seg * 8) = *(uint4*)&tl[nl][seg * 8];
    }
}

// ---------------- register-A MFMA GEMM, K=192 fixed, batched over z ----------------
#define BS_STRIDE 104
template<int TERMS>
__global__ __launch_bounds__(256) void gemm_reg(
    const ushort_t* __restrict__ Ahi, const ushort_t* __restrict__ Alo,
    const ushort_t* __restrict__ BThi, const ushort_t* __restrict__ BTlo,
    float* __restrict__ C, int M, int N,
    long strideA, long strideB, long strideC)
{
    int z = blockIdx.z;
    Ahi += z * strideA; Alo += z * strideA;
    BThi += z * strideB; BTlo += z * strideB;
    C += z * strideC;
    __shared__ ushort_t Bs0[128 * BS_STRIDE];
    __shared__ ushort_t Bs1[128 * BS_STRIDE];
    int t = threadIdx.x;
    int wave = t >> 6, lane = t & 63;
    int l15 = lane & 15, quad = lane >> 4;
    int m0 = blockIdx.y * 64, n0 = blockIdx.x * 128;
    int wm = (wave & 1) * 32, wn = (wave >> 1) * 64;
    floatx4 acc[2][4];
#pragma unroll
    for (int i = 0; i < 2; ++i)
#pragma unroll
        for (int j = 0; j < 4; ++j) acc[i][j] = (floatx4){0.f, 0.f, 0.f, 0.f};

    if (TERMS == 1) {
        short8 af[2][6];
#pragma unroll
        for (int mi = 0; mi < 2; ++mi)
#pragma unroll
            for (int k0 = 0; k0 < 6; ++k0)
                af[mi][k0] = *(const short8*)(Ahi
                    + (long)(m0 + wm + mi * 16 + l15) * 192 + k0 * 32 + quad * 8);
        for (int i = t; i < 3072; i += 256) {
            int r = i / 24, seg = i % 24;
            uint4 v = *(const uint4*)(BThi + (long)(n0 + r) * 192 + seg * 8);
            ushort_t* dst = (seg < 12) ? &Bs0[r * BS_STRIDE + seg * 8]
                                       : &Bs1[r * BS_STRIDE + (seg - 12) * 8];
            *(uint4*)dst = v;
        }
        __syncthreads();
#pragma unroll
        for (int k0 = 0; k0 < 6; ++k0) {
            int ks = k0 * 32 + quad * 8;
            const ushort_t* buf = (ks < 96) ? Bs0 : Bs1;
            int col = (ks < 96) ? ks : ks - 96;
            short8 bf[4];
#pragma unroll
            for (int ni = 0; ni < 4; ++ni)
                bf[ni] = *(const short8*)&buf[(wn + ni * 16 + l15) * BS_STRIDE + col];
#pragma unroll
            for (int mi = 0; mi < 2; ++mi)
#pragma unroll
                for (int ni = 0; ni < 4; ++ni)
                    acc[mi][ni] = __builtin_amdgcn_mfma_f32_16x16x32_bf16(
                        af[mi][k0], bf[ni], acc[mi][ni], 0, 0, 0);
        }
    } else {
#pragma unroll
        for (int kh = 0; kh < 2; ++kh) {
            short8 ah[2][3], al[2][3];
#pragma unroll
            for (int mi = 0; mi < 2; ++mi)
#pragma unroll
                for (int k0 = 0; k0 < 3; ++k0) {
                    long off = (long)(m0 + wm + mi * 16 + l15) * 192
                             + kh * 96 + k0 * 32 + quad * 8;
                    ah[mi][k0] = *(const short8*)(Ahi + off);
                    al[mi][k0] = *(const short8*)(Alo + off);
                }
            if (kh) __syncthreads();
            for (int i = t; i < 1536; i += 256) {
                int r = i / 12, seg = i % 12;
                long goff = (long)(n0 + r) * 192 + kh * 96 + seg * 8;
                *(uint4*)&Bs0[r * BS_STRIDE + seg * 8] = *(const uint4*)(BThi + goff);
                *(uint4*)&Bs1[r * BS_STRIDE + seg * 8] = *(const uint4*)(BTlo + goff);
            }
            __syncthreads();
#pragma unroll
            for (int k0 = 0; k0 < 3; ++k0) {
                int col = k0 * 32 + quad * 8;
                short8 bh[4], bl[4];
#pragma unroll
                for (int ni = 0; ni < 4; ++ni) {
                    bh[ni] = *(const short8*)&Bs0[(wn + ni * 16 + l15) * BS_STRIDE + col];
                    bl[ni] = *(const short8*)&Bs1[(wn + ni * 16 + l15) * BS_STRIDE + col];
                }
#pragma unroll
                for (int mi = 0; mi < 2; ++mi)
#pragma unroll
                    for (int ni = 0; ni < 4; ++ni) {
                        acc[mi][ni] = __builtin_amdgcn_mfma_f32_16x16x32_bf16(
                            ah[mi][k0], bh[ni], acc[mi][ni], 0, 0, 0);
                        acc[mi][ni] = __builtin_amdgcn_mfma_f32_16x16x32_bf16(
                            ah[mi][k0], bl[ni], acc[mi][ni], 0, 0, 0);
                        acc[mi][ni] = __builtin_amdgcn_mfma_f32_16x16x32_bf16(
                            al[mi][k0], bh[ni], acc[mi][ni], 0, 0, 0);
                    }
            }
        }
    }
#pragma unroll
    for (int mi = 0; mi < 2; ++mi)
#pragma unroll
        for (int ni = 0; ni < 4; ++ni) {
            long base = (long)(m0 + wm + mi * 16 + quad * 4) * N + n0 + wn + ni * 16 + l15;
#pragma unroll
            for (int r = 0; r < 4; ++r)
                C[base + (long)r * N] = acc[mi][ni][r];
        }
}

// ---------------- Depthwise 3x3 + fused sum-of-squares (q,k channels) ----------------
__global__ __launch_bounds__(256) void dwconv3x3_lds(
    const float* __restrict__ in, const float* __restrict__ w,
    float* __restrict__ out, float* __restrict__ normsq,
    int c0, int chunk)
{
    __shared__ float tile[10][132];
    int z = blockIdx.z;
    int cl = blockIdx.y;
    int gc = c0 + cl;
    in  += (long)z * chunk * HW + (long)cl * HW;
    out += (long)z * C3 * HW + (long)gc * HW;
    int y0 = blockIdx.x * 8;
    const float* wc = w + gc * 9;
    float wf[9];
#pragma unroll
    for (int i = 0; i < 9; ++i) wf[i] = wc[i];
    int t = threadIdx.x;
    if (t < 10) { tile[t][0] = 0.f; tile[t][129] = 0.f; }
    for (int i = t; i < 320; i += 256) {
        int r = i >> 5, c4 = (i & 31) * 4;
        int gy = y0 - 1 + r;
        float4 v = {0.f, 0.f, 0.f, 0.f};
        if (gy >= 0 && gy < 128) v = *(const float4*)(in + gy * 128 + c4);
        tile[r][1 + c4] = v.x; tile[r][2 + c4] = v.y;
        tile[r][3 + c4] = v.z; tile[r][4 + c4] = v.w;
    }
    __syncthreads();
    int yl = t >> 5, xl = (t & 31) * 4;
    float s0 = 0.f, s1 = 0.f, s2 = 0.f, s3 = 0.f;
#pragma unroll
    for (int r = 0; r < 3; ++r) {
        float c0v = tile[yl + r][xl + 0], c1v = tile[yl + r][xl + 1];
        float c2v = tile[yl + r][xl + 2], c3v = tile[yl + r][xl + 3];
        float c4v = tile[yl + r][xl + 4], c5v = tile[yl + r][xl + 5];
        float w0 = wf[r * 3], w1 = wf[r * 3 + 1], w2 = wf[r * 3 + 2];
        s0 += w0 * c0v + w1 * c1v + w2 * c2v;
        s1 += w0 * c1v + w1 * c2v + w2 * c3v;
        s2 += w0 * c2v + w1 * c3v + w2 * c4v;
        s3 += w0 * c3v + w1 * c4v + w2 * c5v;
    }
    float4 o = {s0, s1, s2, s3};
    *(float4*)(out + (y0 + yl) * 128 + xl) = o;
    if (gc < 2 * DIM) {
        __syncthreads();
        float* red = (float*)tile;
        red[t] = s0 * s0 + s1 * s1 + s2 * s2 + s3 * s3;
        __syncthreads();
        for (int off = 128; off > 0; off >>= 1) {
            if (t < off) red[t] += red[t + off];
            __syncthreads();
        }
        if (t == 0) atomicAdd(&normsq[z * 512 + gc], red[0]);
    }
}

// ---------------- QK^T partials, NO atomics: partial[p][bh][48][48] ----------------
// grid (NCHUNK, HEADS, BB), block 256; n-chunk = 256 cols, staged in 4 rounds of 64.
__global__ __launch_bounds__(256) void attn_partial2(
    const float* __restrict__ dw, float* __restrict__ partial)
{
    int z = blockIdx.z, h = blockIdx.y, pidx = blockIdx.x;
    int n0 = pidx * (HW / NCHUNK);
    dw += (long)z * C3 * HW;
    __shared__ float qs[48][68];     // 68 stride: 2-way banks only
    __shared__ float ks[48][68];
    const float* qb = dw + (long)(h * CH) * HW + n0;
    const float* kb = dw + (long)(DIM + h * CH) * HW + n0;
    int t = threadIdx.x;
    int tx = t & 15, ty = t >> 4;
    int c0 = ty * 3, d0 = tx * 3;
    float acc[3][3] = {};
#pragma unroll
    for (int rnd = 0; rnd < 4; ++rnd) {
        if (rnd) __syncthreads();
#pragma unroll
        for (int i = 0; i < 3; ++i) {
            int f = t + i * 256;          // 768 float4 slots = 48 rows x 16
            int row = f >> 4, c4 = (f & 15) * 4;
            float4 qv = *(const float4*)(qb + (long)row * HW + rnd * 64 + c4);
            float4 kv = *(const float4*)(kb + (long)row * HW + rnd * 64 + c4);
            *(float4*)&qs[row][c4] = qv;
            *(float4*)&ks[row][c4] = kv;
        }
        __syncthreads();
        for (int nv = 0; nv < 16; ++nv) {
            float4 qa[3], kb4[3];
#pragma unroll
            for (int i = 0; i < 3; ++i) qa[i] = *(const float4*)&qs[c0 + i][nv * 4];
#pragma unroll
            for (int j = 0; j < 3; ++j) kb4[j] = *(const float4*)&ks[d0 + j][nv * 4];
#pragma unroll
            for (int i = 0; i < 3; ++i)
#pragma unroll
                for (int j = 0; j < 3; ++j)
                    acc[i][j] += qa[i].x * kb4[j].x + qa[i].y * kb4[j].y
                               + qa[i].z * kb4[j].z + qa[i].w * kb4[j].w;
        }
    }
    float* pp = partial + ((long)(pidx * 16 + z * HEADS + h)) * 2304;
#pragma unroll
    for (int i = 0; i < 3; ++i)
#pragma unroll
        for (int j = 0; j < 3; ++j)
            pp[(c0 + i) * CH + d0 + j] = acc[i][j];
}

// ---------------- top-k softmax combine: reduce partials inline; wave per row ----------------
// grid (48, BB), block 256 (4 waves = 4 rows)
__global__ __launch_bounds__(256) void topk_combine2(
    const float* __restrict__ partial, const float* __restrict__ normsq,
    const float* __restrict__ temp, const float* __restrict__ attn_w,
    float* __restrict__ Wc)
{
    int z = blockIdx.y;
    int wave = threadIdx.x >> 6, lane = threadIdx.x & 63;
    int rid = blockIdx.x * 4 + wave;   // 0..191 = h*48 + c
    int c = rid % CH, h = rid / CH;
    int d = lane;
    float a = -INFINITY;
    if (d < 48) {
        float s = 0.f;
        const float* pp = partial + (long)(z * HEADS + h) * 2304 + c * CH + d;
        for (int p = 0; p < NCHUNK; ++p) s += pp[(long)p * 16 * 2304];
        float invq = 1.0f / fmaxf(sqrtf(normsq[z * 512 + h * CH + c]), 1e-12f);
        float invk = 1.0f / fmaxf(sqrtf(normsq[z * 512 + DIM + h * CH + d]), 1e-12f);
        a = s * invq * invk * temp[h];
    }
    float m = a;
#pragma unroll
    for (int off = 32; off > 0; off >>= 1) m = fmaxf(m, __shfl_xor(m, off, 64));
    float e = (d < 48) ? expf(a - m) : 0.f;
    int rank = 0;
    for (int j = 0; j < 48; ++j) {
        float aj = __shfl(a, j, 64);
        rank += (aj > a) || (aj == a && j < d);
    }
    // k = int(48*rate) in IEEE double: {24, 32, 36, 38} (48*(2/3) rounds UP to 32.0)
    const int kv[4] = {24, 32, 36, 38};
    float s = 0.f;
#pragma unroll
    for (int i = 0; i < 4; ++i) {
        float contrib = (d < 48 && rank < kv[i]) ? e : 0.f;
#pragma unroll
        for (int off = 32; off > 0; off >>= 1) contrib += __shfl_xor(contrib, off, 64);
        s += (rank < kv[i]) ? attn_w[i] / contrib : 0.f;
    }
    if (d < 48) Wc[(long)z * 9216 + (long)rid * CH + d] = e * s;
}

// ---------------- M[z][o, h*48+d] = sum_ch wproj[o, h*48+ch] * Wc[z][h,ch,d] -> bf16 ----------------
__global__ __launch_bounds__(256) void build_m(
    const float* __restrict__ wproj, const float* __restrict__ Wc,
    ushort_t* __restrict__ Mb)
{
    int z = blockIdx.y;
    int idx = blockIdx.x * 256 + threadIdx.x;
    if (idx >= DIM * DIM) return;
    int cg = idx % DIM;
    int o  = idx / DIM;
    int h = cg / CH, d = cg % CH;
    const float* wp = wproj + o * DIM + h * CH;
    const float* wcc = Wc + (long)z * 9216 + (long)h * CH * CH + d;
    float s = 0.f;
#pragma unroll
    for (int ch = 0; ch < CH; ++ch) s += wp[ch] * wcc[ch * CH];
    Mb[(long)z * DIM * DIM + idx] = f2bf(s);
}

extern "C" void kernel_launch(void* const* d_in, const int* in_sizes, int n_in,
                              void* d_out, int out_size, void* d_ws, size_t ws_size,
                              hipStream_t stream) {
    const float* x      = (const float*)d_in[0];   // [4,192,128,128]
    const float* w_qkv  = (const float*)d_in[1];   // [576,192]
    const float* w_dw   = (const float*)d_in[2];   // [576,9]
    const float* w_proj = (const float*)d_in[3];   // [192,192]
    const float* temper = (const float*)d_in[4];   // [4]
    const float* attn_w = (const float*)d_in[5];   // [4]
    float* out = (float*)d_out;                    // [4,192,128,128]

    // Workspace (256 MiB). Total used ~250 MiB.
    char* p = (char*)d_ws;
    float* dw        = (float*)p;      p += (long)BB * C3 * HW * 4;       // 151.0 MB
    ushort_t* xT_hi  = (ushort_t*)p;   p += (long)BB * HW * DIM * 2;      // 25.2 MB
    ushort_t* xT_lo  = (ushort_t*)p;   p += (long)BB * HW * DIM * 2;      // 25.2 MB
    ushort_t* wq_hi  = (ushort_t*)p;   p += (long)C3 * DIM * 2;
    ushort_t* wq_lo  = (ushort_t*)p;   p += (long)C3 * DIM * 2;
    float* normsq    = (float*)p;      p += (long)BB * 512 * 4;
    float* partial   = (float*)p;      p += (long)NCHUNK * 16 * 2304 * 4; // 9.4 MB
    float* Wc        = (float*)p;      p += (long)BB * 9216 * 4;
    ushort_t* Mb     = (ushort_t*)p;   p += (long)BB * DIM * DIM * 2;
    float* pre       = (float*)p;      // BB * chunk * HW floats
    long avail = (long)ws_size - (long)(p - (char*)d_ws);
    int chunk = 64;                                         // 16.8 MB fallback
    if (avail >= (long)BB * 192 * HW * 4) chunk = 192;      // 50.3 MB

    // 0a. zero normsq
    zero_init<<<(BB * 512 + 255) / 256, 256, 0, stream>>>(normsq, BB * 512);
    // 0b. weights -> split bf16
    convert_split<<<(C3 * DIM + 255) / 256, 256, 0, stream>>>(
        w_qkv, wq_hi, wq_lo, C3 * DIM);
    // 0c. x -> xT hi/lo bf16, all batches
    tconv<<<dim3(HW / 64, DIM / 64, BB), 256, 0, stream>>>(
        x, xT_hi, xT_lo, 1, (long)DIM * HW);

    // 1+2. qkv 1x1 MFMA + dwconv3x3(+sumsq). q,k chunks: TERMS=3; v chunks: TERMS=1.
    for (int c0 = 0; c0 < C3; c0 += chunk) {
        if (c0 < 2 * DIM)
            gemm_reg<3><<<dim3(HW / 128, chunk / 64, BB), 256, 0, stream>>>(
                wq_hi + (long)c0 * DIM, wq_lo + (long)c0 * DIM, xT_hi, xT_lo,
                pre, chunk, HW, 0L, (long)HW * DIM, (long)chunk * HW);
        else
            gemm_reg<1><<<dim3(HW / 128, chunk / 64, BB), 256, 0, stream>>>(
                wq_hi + (long)c0 * DIM, wq_hi + (long)c0 * DIM, xT_hi, xT_hi,
                pre, chunk, HW, 0L, (long)HW * DIM, (long)chunk * HW);
        dwconv3x3_lds<<<dim3(16, chunk, BB), 256, 0, stream>>>(
            pre, w_dw, dw, normsq, c0, chunk);
    }
    // 3. QK^T partials (no atomics)
    attn_partial2<<<dim3(NCHUNK, HEADS, BB), 256, 0, stream>>>(dw, partial);
    // 4. top-k softmax combine (reduce partials + norms inline)
    topk_combine2<<<dim3(48, BB), 256, 0, stream>>>(
        partial, normsq, temper, attn_w, Wc);
    // 5. fold proj into per-batch [192,192] bf16
    build_m<<<dim3((DIM * DIM + 255) / 256, BB), 256, 0, stream>>>(w_proj, Wc, Mb);
    // 6. v -> vT bf16 (hi only; reuse xT_hi)
    tconv<<<dim3(HW / 64, DIM / 64, BB), 256, 0, stream>>>(
        dw + (long)2 * DIM * HW, xT_hi, xT_lo, 0, (long)C3 * HW);
    // 7. out = M @ v (MFMA, single term)
    gemm_reg<1><<<dim3(HW / 128, DIM / 64, BB), 256, 0, stream>>>(
        Mb, Mb, xT_hi, xT_hi, out, DIM, HW,
        (long)DIM * DIM, (long)HW * DIM, (long)DIM * HW);
}